// Round 1
// baseline (288.866 us; speedup 1.0000x reference)
//
#include <hip/hip_runtime.h>
#include <hip/hip_bf16.h>

// FeatureSimilarity l2: out[i][j] = -sqrt(max(sq[i] + sq[j] - 2*<f_i, f_j>, 0))
// N=8192, D=128, fp32 in/out. Write-bound floor ~42-90 us (268 MB out).
//
// R1 (279.1 us, harness-verified): swizzled bf16 fragment layout fbT so
// fragment loads are coalesced 1 KB dwordx4; transposed epilogue writes
// (bitwise-exact by symmetry) so stores are contiguous float4.
//
// R2 change (this round, single variable):
//   Non-temporal stores for the 256 MiB `out` stream.
//   Theory: the write-back/write-allocate out stream evicts the 2 MB fbT
//   working set from each XCD's 4 MB L2, turning every block's 128 KB of
//   fragment re-reads into ~600-900 cy L3/HBM misses that ~3-4 waves/SIMD
//   cannot hide -> latency-bound GEMM (explains 0.96 TB/s effective, and
//   why R1's pure-coalescing fixes only bought 14 us).
//   `out` is never re-read, so nt (no L2 allocation) is semantically free.

typedef __attribute__((ext_vector_type(8))) short short8;    // 8 bf16 = 4 VGPRs
typedef __attribute__((ext_vector_type(4))) float float4v;   // MFMA acc

#define FS_N 8192
#define FS_D 128

// RNE fp32 -> bf16 (matches MFMA input rounding)
static __device__ __forceinline__ unsigned short f32_to_bf16_rne(float x) {
    unsigned u = __float_as_uint(x);
    u += 0x7FFFu + ((u >> 16) & 1u);
    return (unsigned short)(u >> 16);
}
static __device__ __forceinline__ float bf16_to_f32(unsigned short b) {
    return __uint_as_float(((unsigned)b) << 16);
}

// Kernel 1: fp32 F -> bf16 in MFMA-fragment-swizzled layout
//   fbT[((rt*4 + ks)*64 + quad*16 + l15)*8 + e]  holds  F_bf16[rt*16+l15][ks*32+quad*8+e]
// and sq[row] = sum(bf16(f_row)^2) in fp32.
// One block = one 16-row tile (rt). thread t: row_local = t>>4, k-group g = t&15.
__global__ __launch_bounds__(256) void fs_convert_kernel(
        const float* __restrict__ in, unsigned short* __restrict__ fbT,
        float* __restrict__ sq) {
    const int rt = blockIdx.x;           // 0..511
    const int t  = threadIdx.x;
    const int rl = t >> 4;               // row within tile, 0..15
    const int g  = t & 15;               // 8-element k-group, 0..15
    const int row = rt * 16 + rl;

    const float4* src = (const float4*)(in + row * FS_D + g * 8);
    const float4 v0 = src[0];
    const float4 v1 = src[1];

    short8 packed;
    float s = 0.0f;
    {
        const float vv[8] = {v0.x, v0.y, v0.z, v0.w, v1.x, v1.y, v1.z, v1.w};
        #pragma unroll
        for (int e = 0; e < 8; ++e) {
            const unsigned short b = f32_to_bf16_rne(vv[e]);
            packed[e] = (short)b;
            const float f = bf16_to_f32(b);
            s += f * f;
        }
    }

    // swizzled store: ks = g>>2, quad = g&3, lane_in_frag = quad*16 + rl
    const int ks   = g >> 2;
    const int quad = g & 3;
    short8* dst = (short8*)(fbT + (((size_t)(rt * 4 + ks) * 64) + quad * 16 + rl) * 8);
    *dst = packed;

    // reduce partial sums across the 16 lanes sharing this row (xor<16 stays in group)
    #pragma unroll
    for (int off = 8; off > 0; off >>= 1) s += __shfl_xor(s, off);
    if (g == 0) sq[row] = s;
}

// Kernel 2: one 128x128 output tile per block; 4 waves in 2x2, each 64x64
// via 4x4 tiles of 16x16x32 bf16 MFMA, K=128 = 4 ksteps. Fragment loads are
// coalesced dwordx4 from the swizzled L2-resident fbT.
__global__ __launch_bounds__(256) void fs_gemm_kernel(
        const unsigned short* __restrict__ fbT, const float* __restrict__ sq,
        float* __restrict__ out) {
    const int ti   = blockIdx.x;          // A row-tile (128 rows)
    const int tj   = blockIdx.y;          // B row-tile (= output cols)
    const int wid  = threadIdx.x >> 6;
    const int lane = threadIdx.x & 63;
    const int wm   = wid >> 1, wn = wid & 1;
    const int l15  = lane & 15;
    const int quad = lane >> 4;

    const int arow = ti * 128 + wm * 64;  // A rows this wave covers (+0..63)
    const int brow = tj * 128 + wn * 64;  // B rows (= output cols)

    // fragment base: rt16 index (16-row granularity)
    const int rta = ti * 8 + wm * 4;      // +m
    const int rtb = tj * 8 + wn * 4;      // +n

    float4v acc[4][4];
    #pragma unroll
    for (int m = 0; m < 4; ++m)
        #pragma unroll
        for (int n = 0; n < 4; ++n)
            acc[m][n] = (float4v){0.f, 0.f, 0.f, 0.f};

    #pragma unroll
    for (int ks = 0; ks < 4; ++ks) {
        short8 a[4], b[4];
        #pragma unroll
        for (int m = 0; m < 4; ++m)
            a[m] = *(const short8*)(fbT + (size_t)((rta + m) * 4 + ks) * 512 + lane * 8);
        #pragma unroll
        for (int n = 0; n < 4; ++n)
            b[n] = *(const short8*)(fbT + (size_t)((rtb + n) * 4 + ks) * 512 + lane * 8);
        #pragma unroll
        for (int m = 0; m < 4; ++m)
            #pragma unroll
            for (int n = 0; n < 4; ++n)
                acc[m][n] = __builtin_amdgcn_mfma_f32_16x16x32_bf16(
                    a[m], b[n], acc[m][n], 0, 0, 0);
    }

    // Epilogue. C/D layout (16x16): col = l15, row = quad*4 + r.
    // Write transposed (out is symmetric, MFMA dot is bitwise symmetric):
    // out[col*N + row], so each lane stores float4 over r (consecutive rows).
    // R2: non-temporal stores — do not allocate the 256 MiB stream in L2,
    // keeping fbT (2 MB) L2-resident for every block's fragment reads.
    #pragma unroll
    for (int n = 0; n < 4; ++n) {
        const int   col = brow + n * 16 + l15;
        const float sqc = sq[col];
        float* outcol = out + (size_t)col * FS_N;
        #pragma unroll
        for (int m = 0; m < 4; ++m) {
            const int rbase = arow + m * 16 + quad * 4;
            const float4v sqr = *(const float4v*)(sq + rbase);
            float4v o;
            #pragma unroll
            for (int r = 0; r < 4; ++r) {
                float d2 = sqr[r] + sqc - 2.0f * acc[m][n][r];
                d2 = fmaxf(d2, 0.0f);
                o[r] = -__builtin_sqrtf(d2);
            }
            __builtin_nontemporal_store(o, (float4v*)(outcol + rbase));
        }
    }
}

extern "C" void kernel_launch(void* const* d_in, const int* in_sizes, int n_in,
                              void* d_out, int out_size, void* d_ws, size_t ws_size,
                              hipStream_t stream) {
    const float* features = (const float*)d_in[0];
    float*       out      = (float*)d_out;

    // ws layout: [0, 2MB) swizzled bf16 features; then fp32 row sum-of-squares
    unsigned short* fbT = (unsigned short*)d_ws;
    float*          sq  = (float*)((char*)d_ws + (size_t)FS_N * FS_D * sizeof(unsigned short));

    fs_convert_kernel<<<FS_N / 16, 256, 0, stream>>>(features, fbT, sq);

    dim3 grid(FS_N / 128, FS_N / 128);
    fs_gemm_kernel<<<grid, 256, 0, stream>>>(fbT, sq, out);
}

// Round 2
// 274.601 us; speedup vs baseline: 1.0519x; 1.0519x over previous
//
#include <hip/hip_runtime.h>
#include <hip/hip_bf16.h>

// FeatureSimilarity l2: out[i][j] = -sqrt(max(sq[i] + sq[j] - 2*<f_i, f_j>, 0))
// N=8192, D=128, fp32 in/out. Write floor ~43 us (268 MB @ 6.3 TB/s, proven
// reachable by the harness fill kernel on this box).
//
// R1 (279.1 us): swizzled bf16 fragment layout fbT -> coalesced dwordx4
// fragment loads; transposed epilogue stores (bitwise-exact by symmetry).
// R2 (288.9 us): nt stores — REFUTED L2-pollution theory (+10 us). Reverted.
// R3 (this round): occupancy/overlap restructure.
//   Theory: gemm (~110-166 us vs ~60 us arithmetic floor) is phase-locked
//   latency-bound: acc[4][4] (~160 VGPR) -> ~3 blocks/CU, every wave runs
//   loads -> 64 MFMA -> sqrt epilogue -> 16 KB store burst serially, so the
//   store pipe sees bursts + idle gaps (0.96 TB/s effective vs 6.3 healthy).
//   Change: wave tile 64x32 (acc[4][2]=32 VGPR), block 128x64, grid 64x128,
//   __launch_bounds__(256,4) to cap 128 VGPR -> ~4+ blocks/CU, staggered
//   phases, half-size store bursts.

typedef __attribute__((ext_vector_type(8))) short short8;    // 8 bf16 = 4 VGPRs
typedef __attribute__((ext_vector_type(4))) float float4v;   // MFMA acc

#define FS_N 8192
#define FS_D 128

// RNE fp32 -> bf16 (matches MFMA input rounding)
static __device__ __forceinline__ unsigned short f32_to_bf16_rne(float x) {
    unsigned u = __float_as_uint(x);
    u += 0x7FFFu + ((u >> 16) & 1u);
    return (unsigned short)(u >> 16);
}
static __device__ __forceinline__ float bf16_to_f32(unsigned short b) {
    return __uint_as_float(((unsigned)b) << 16);
}

// Kernel 1: fp32 F -> bf16 in MFMA-fragment-swizzled layout
//   fbT[((rt*4 + ks)*64 + quad*16 + l15)*8 + e]  holds  F_bf16[rt*16+l15][ks*32+quad*8+e]
// and sq[row] = sum(bf16(f_row)^2) in fp32.
__global__ __launch_bounds__(256) void fs_convert_kernel(
        const float* __restrict__ in, unsigned short* __restrict__ fbT,
        float* __restrict__ sq) {
    const int rt = blockIdx.x;           // 0..511
    const int t  = threadIdx.x;
    const int rl = t >> 4;               // row within tile, 0..15
    const int g  = t & 15;               // 8-element k-group, 0..15
    const int row = rt * 16 + rl;

    const float4* src = (const float4*)(in + row * FS_D + g * 8);
    const float4 v0 = src[0];
    const float4 v1 = src[1];

    short8 packed;
    float s = 0.0f;
    {
        const float vv[8] = {v0.x, v0.y, v0.z, v0.w, v1.x, v1.y, v1.z, v1.w};
        #pragma unroll
        for (int e = 0; e < 8; ++e) {
            const unsigned short b = f32_to_bf16_rne(vv[e]);
            packed[e] = (short)b;
            const float f = bf16_to_f32(b);
            s += f * f;
        }
    }

    // swizzled store: ks = g>>2, quad = g&3, lane_in_frag = quad*16 + rl
    const int ks   = g >> 2;
    const int quad = g & 3;
    short8* dst = (short8*)(fbT + (((size_t)(rt * 4 + ks) * 64) + quad * 16 + rl) * 8);
    *dst = packed;

    #pragma unroll
    for (int off = 8; off > 0; off >>= 1) s += __shfl_xor(s, off);
    if (g == 0) sq[row] = s;
}

// Kernel 2: one 128x64 output tile per block; 4 waves in 2x2, each 64x32
// via 4x2 tiles of 16x16x32 bf16 MFMA, K=128 = 4 ksteps.
// Small wave tile -> acc[4][2]=32 VGPRs -> >=4 blocks/CU for phase overlap.
__global__ __launch_bounds__(256, 4) void fs_gemm_kernel(
        const unsigned short* __restrict__ fbT, const float* __restrict__ sq,
        float* __restrict__ out) {
    const int ti   = blockIdx.x;          // A row-tile (128 rows), 0..63
    const int tj   = blockIdx.y;          // B row-tile (64 output cols), 0..127
    const int wid  = threadIdx.x >> 6;
    const int lane = threadIdx.x & 63;
    const int wm   = wid >> 1, wn = wid & 1;
    const int l15  = lane & 15;
    const int quad = lane >> 4;

    const int arow = ti * 128 + wm * 64;  // A rows this wave covers (+0..63)
    const int brow = tj * 64  + wn * 32;  // B rows (= output cols, +0..31)

    // fragment base: rt16 index (16-row granularity)
    const int rta = ti * 8 + wm * 4;      // +m (0..3)
    const int rtb = tj * 4 + wn * 2;      // +n (0..1)

    float4v acc[4][2];
    #pragma unroll
    for (int m = 0; m < 4; ++m)
        #pragma unroll
        for (int n = 0; n < 2; ++n)
            acc[m][n] = (float4v){0.f, 0.f, 0.f, 0.f};

    #pragma unroll
    for (int ks = 0; ks < 4; ++ks) {
        short8 a[4], b[2];
        #pragma unroll
        for (int m = 0; m < 4; ++m)
            a[m] = *(const short8*)(fbT + (size_t)((rta + m) * 4 + ks) * 512 + lane * 8);
        #pragma unroll
        for (int n = 0; n < 2; ++n)
            b[n] = *(const short8*)(fbT + (size_t)((rtb + n) * 4 + ks) * 512 + lane * 8);
        #pragma unroll
        for (int m = 0; m < 4; ++m)
            #pragma unroll
            for (int n = 0; n < 2; ++n)
                acc[m][n] = __builtin_amdgcn_mfma_f32_16x16x32_bf16(
                    a[m], b[n], acc[m][n], 0, 0, 0);
    }

    // Epilogue. C/D layout (16x16): col = l15, row = quad*4 + r.
    // Write transposed (out symmetric, MFMA dot bitwise symmetric):
    // out[col*N + row]; each lane stores a contiguous float4 over r.
    #pragma unroll
    for (int n = 0; n < 2; ++n) {
        const int   col = brow + n * 16 + l15;
        const float sqc = sq[col];
        float* outcol = out + (size_t)col * FS_N;
        #pragma unroll
        for (int m = 0; m < 4; ++m) {
            const int rbase = arow + m * 16 + quad * 4;
            const float4v sqr = *(const float4v*)(sq + rbase);
            float4v o;
            #pragma unroll
            for (int r = 0; r < 4; ++r) {
                float d2 = sqr[r] + sqc - 2.0f * acc[m][n][r];
                d2 = fmaxf(d2, 0.0f);
                o[r] = -__builtin_sqrtf(d2);
            }
            *(float4v*)(outcol + rbase) = o;
        }
    }
}

extern "C" void kernel_launch(void* const* d_in, const int* in_sizes, int n_in,
                              void* d_out, int out_size, void* d_ws, size_t ws_size,
                              hipStream_t stream) {
    const float* features = (const float*)d_in[0];
    float*       out      = (float*)d_out;

    // ws layout: [0, 2MB) swizzled bf16 features; then fp32 row sum-of-squares
    unsigned short* fbT = (unsigned short*)d_ws;
    float*          sq  = (float*)((char*)d_ws + (size_t)FS_N * FS_D * sizeof(unsigned short));

    fs_convert_kernel<<<FS_N / 16, 256, 0, stream>>>(features, fbT, sq);

    dim3 grid(FS_N / 128, FS_N / 64);
    fs_gemm_kernel<<<grid, 256, 0, stream>>>(fbT, sq, out);
}